// Round 5
// baseline (155.798 us; speedup 1.0000x reference)
//
#include <hip/hip_runtime.h>
#include <hip/hip_bf16.h>

// Problem: MultiViewDGT_51745765982512
//   d_in[0] H [N,128] f32, d_in[1] port_w [L] f32, d_in[2] anchor [B] i32,
//   d_in[3] pf_gid [B] i32, d_in[4] port_nodes [L] i32, d_in[5] port_len [G] i32
//   out = concat(V_abs [B,128], V_sgn [B,128]) f32
//
// R5: fully fused. R4 showed the gather is bound by compulsory per-XCD L2
// fill of Hb (8 XCDs x 16 MB at ~3.3 TB/s L3->L2) — request dedup didn't
// move it. Remaining fat was structural: per_sample re-read pw/pn + Sabs
// round-trip. Now: init builds a gid->samples CSR (single block, 64 KB LDS
// counters) alongside H->bf16 convert and the line-offset scan; group_sums
// keeps S_abs in registers, tracks per-sample LOO self-weights in-loop
// (cap 8/group, re-scan fallback for overflow), and writes V_abs/V_sgn
// directly. One gather pass, no intermediate S_abs in memory.

#define DDIM 128
#define SMAX 8
#define MAXG_LDS 16384

__device__ inline unsigned bf_rne(float x) {
    unsigned u = __float_as_uint(x);
    return (u + 0x7FFFu + ((u >> 16) & 1u)) >> 16;
}

__device__ inline void unpack2(unsigned d, float& lo, float& hi) {
    lo = __uint_as_float(d << 16);
    hi = __uint_as_float(d & 0xFFFF0000u);
}

// Block roles: [0,nconv) convert H->bf16; nconv: gid->sample CSR (+ zero
// invalid-sample outputs); nconv+1: exclusive scan of plen -> offs.
__global__ __launch_bounds__(1024) void init_kernel(
    const float4* __restrict__ H4, uint2* __restrict__ Hb, int n4,
    const int* __restrict__ plen, int* __restrict__ offs, int G,
    const int* __restrict__ pf_gid, int* __restrict__ sstart,
    int* __restrict__ slist, float* __restrict__ out, int B, int nconv) {
    __shared__ int shm[MAXG_LDS];   // 64 KB: counters / scan scratch
    const int t = threadIdx.x;
    const int bb = blockIdx.x;

    if (bb < nconv) {
        const int i = bb * 1024 + t;
        if (i < n4) {
            const float4 v = H4[i];
            uint2 o;
            o.x = bf_rne(v.x) | (bf_rne(v.y) << 16);
            o.y = bf_rne(v.z) | (bf_rne(v.w) << 16);
            Hb[i] = o;
        }
        return;
    }

    if (bb == nconv) {
        // ---- build gid -> samples CSR (G <= MAXG_LDS guaranteed by host) ----
        for (int i = t; i < G; i += 1024) shm[i] = 0;
        __syncthreads();
        for (int i = t; i < B; i += 1024) {
            const int g = pf_gid[i];
            if (g >= 0 && g < G) {
                atomicAdd(&shm[g], 1);
            } else {
                // invalid sample: reference outputs zeros; write them now
                float4* oa = (float4*)(out + (size_t)i * DDIM);
                float4* os = (float4*)(out + ((size_t)B + i) * DDIM);
                const float4 z = make_float4(0.f, 0.f, 0.f, 0.f);
                for (int k = 0; k < DDIM / 4; ++k) { oa[k] = z; os[k] = z; }
            }
        }
        __syncthreads();
        // exclusive scan of shm[0..G-1]; 1024 threads x chunk
        const int chunk = (G + 1023) >> 10;   // 16 when G=16384
        int c[16];
        int local = 0;
        #pragma unroll
        for (int k = 0; k < 16; ++k) {
            const int idx = t * chunk + k;
            c[k] = (k < chunk && idx < G) ? shm[idx] : 0;
            local += c[k];
        }
        __syncthreads();
        const int lane = t & 63, wid = t >> 6;
        int incl = local;
        #pragma unroll
        for (int m = 1; m < 64; m <<= 1) {
            int v = __shfl_up(incl, m);
            if (lane >= m) incl += v;
        }
        if (lane == 63) shm[wid] = incl;   // 16 wave totals
        __syncthreads();
        int woff = 0;
        for (int i = 0; i < wid; ++i) woff += shm[i];
        const int excl = woff + incl - local;
        __syncthreads();
        int run = excl;
        #pragma unroll
        for (int k = 0; k < 16; ++k) {
            const int idx = t * chunk + k;
            if (k < chunk && idx < G) {
                sstart[idx] = run;
                shm[idx] = run;
                run += c[k];
            }
        }
        if (t == 1023) sstart[G] = run;
        __syncthreads();
        // scatter sample ids
        for (int i = t; i < B; i += 1024) {
            const int g = pf_gid[i];
            if (g >= 0 && g < G) {
                const int pos = atomicAdd(&shm[g], 1);
                slist[pos] = i;
            }
        }
        return;
    }

    // ---- scan role: exclusive prefix sum of plen -> offs ----
    const int chunk = (G + 1023) >> 10;
    const int lo = min(t * chunk, G);
    const int hi = min(lo + chunk, G);
    int s = 0;
    for (int i = lo; i < hi; ++i) s += plen[i];
    shm[t] = s;
    __syncthreads();
    #pragma unroll
    for (int ofs = 1; ofs < 1024; ofs <<= 1) {
        int v = (t >= ofs) ? shm[t - ofs] : 0;
        __syncthreads();
        shm[t] += v;
        __syncthreads();
    }
    int run = shm[t] - s;
    for (int i = lo; i < hi; ++i) { offs[i] = run; run += plen[i]; }
}

// One wave per used group: gather + stats + per-sample LOO + epilogue.
// Gather: 4 rows per dwordx4 (quarter q=lane>>4 row jj+q, s=lane&15 owns
// dims [8s,8s+8)). After quarter-combine every lane has full sums.
__global__ __launch_bounds__(256) void group_fused(
    const unsigned short* __restrict__ Hb,
    const float* __restrict__ pw, const int* __restrict__ pn,
    const int* __restrict__ plen, const int* __restrict__ offs,
    const int* __restrict__ sstart, const int* __restrict__ slist,
    const int* __restrict__ anchor_idx,
    float* __restrict__ out, int B, int G) {
    const int g = blockIdx.x * (blockDim.x >> 6) + (threadIdx.x >> 6);
    const int lane = threadIdx.x & 63;
    const int q = lane >> 4;
    const int s = lane & 15;
    if (g >= G) return;

    const int slo = sstart[g];
    const int shi = sstart[g + 1];
    const int count = shi - slo;
    if (count == 0) return;   // unused group: no sample references it

    const int off = offs[g];
    const int len = plen[g];

    // preload up to SMAX sample ids + anchors (wave-uniform scalar loads)
    int sid[SMAX], anc[SMAX];
    #pragma unroll
    for (int i = 0; i < SMAX; ++i) {
        sid[i] = (i < count) ? slist[slo + i] : -1;
        anc[i] = (sid[i] >= 0) ? anchor_idx[sid[i]] : -1;
    }

    float acc[8] = {0.f, 0.f, 0.f, 0.f, 0.f, 0.f, 0.f, 0.f};
    float selfa[SMAX], selfs[SMAX];
    #pragma unroll
    for (int i = 0; i < SMAX; ++i) { selfa[i] = 0.f; selfs[i] = 0.f; }
    float laWa = 0.f, laWs = 0.f;

    for (int base = 0; base < len; base += 64) {
        const int jmax = min(64, len - base);
        float wl = 0.f;
        int nl = -1;  // padding: w=0, node=-1 never matches an anchor
        if (lane < jmax) {
            wl = pw[off + base + lane];
            nl = pn[off + base + lane];
        }
        const float wla = fabsf(wl);
        laWa += wla;
        laWs += wl;
        #pragma unroll
        for (int i = 0; i < SMAX; ++i) {
            if (nl == anc[i]) { selfa[i] += wla; selfs[i] += wl; }
        }

        #pragma unroll 8
        for (int jj = 0; jj < 64; jj += 4) {
            const float ww = fabsf(__shfl(wl, jj + q));
            const int row = __shfl(nl, jj + q);
            const uint4 h = *((const uint4*)(Hb + (size_t)row * DDIM) + s);
            float f0, f1, f2, f3, f4, f5, f6, f7;
            unpack2(h.x, f0, f1);
            unpack2(h.y, f2, f3);
            unpack2(h.z, f4, f5);
            unpack2(h.w, f6, f7);
            acc[0] = fmaf(ww, f0, acc[0]);
            acc[1] = fmaf(ww, f1, acc[1]);
            acc[2] = fmaf(ww, f2, acc[2]);
            acc[3] = fmaf(ww, f3, acc[3]);
            acc[4] = fmaf(ww, f4, acc[4]);
            acc[5] = fmaf(ww, f5, acc[5]);
            acc[6] = fmaf(ww, f6, acc[6]);
            acc[7] = fmaf(ww, f7, acc[7]);
        }
    }

    // reductions -> uniform on all lanes
    #pragma unroll
    for (int m = 32; m; m >>= 1) {
        laWa += __shfl_xor(laWa, m);
        laWs += __shfl_xor(laWs, m);
    }
    #pragma unroll
    for (int i = 0; i < SMAX; ++i) {
        if (i < count) {
            #pragma unroll
            for (int m = 32; m; m >>= 1) {
                selfa[i] += __shfl_xor(selfa[i], m);
                selfs[i] += __shfl_xor(selfs[i], m);
            }
        }
    }
    #pragma unroll
    for (int k = 0; k < 8; ++k) {
        acc[k] += __shfl_xor(acc[k], 16);
        acc[k] += __shfl_xor(acc[k], 32);
    }

    // epilogue per sample
    const int nmain = min(count, SMAX);
    for (int i = 0; i < nmain; ++i) {
        const int sb = sid[i];
        const float sa = selfa[i], ss = selfs[i];
        const float denom = fmaxf(laWa - sa, 1e-12f);
        const float scale = (laWs - ss) / denom;

        const uint4 ha = *((const uint4*)(Hb + (size_t)anc[i] * DDIM) + s);
        float hv[8];
        unpack2(ha.x, hv[0], hv[1]);
        unpack2(ha.y, hv[2], hv[3]);
        unpack2(ha.z, hv[4], hv[5]);
        unpack2(ha.w, hv[6], hv[7]);

        float v[8];
        float n2 = 0.f;
        #pragma unroll
        for (int k = 0; k < 8; ++k) {
            v[k] = (acc[k] - sa * hv[k]) / denom;
            n2 = fmaf(v[k], v[k], n2);
        }
        #pragma unroll
        for (int m = 32; m; m >>= 1) n2 += __shfl_xor(n2, m);
        n2 *= 0.25f;  // 4 duplicated quarters
        const float na = sqrtf(n2);
        const float invA = 1.0f / fmaxf(na, 1e-6f);
        const float ns = fabsf(scale) * na;
        const float sgnscale = (ns > 0.f) ? (scale / fmaxf(ns, 1e-6f)) : scale;

        if (q == 0) {
            float4* oa = (float4*)(out + (size_t)sb * DDIM);
            oa[2 * s] = make_float4(v[0] * invA, v[1] * invA, v[2] * invA, v[3] * invA);
            oa[2 * s + 1] = make_float4(v[4] * invA, v[5] * invA, v[6] * invA, v[7] * invA);
        } else if (q == 1) {
            float4* os = (float4*)(out + ((size_t)B + sb) * DDIM);
            os[2 * s] = make_float4(v[0] * sgnscale, v[1] * sgnscale, v[2] * sgnscale, v[3] * sgnscale);
            os[2 * s + 1] = make_float4(v[4] * sgnscale, v[5] * sgnscale, v[6] * sgnscale, v[7] * sgnscale);
        }
    }

    // overflow samples (count > SMAX, ~0.1% of groups): re-scan lines
    for (int i = SMAX; i < count; ++i) {
        const int sb = slist[slo + i];
        const int an = anchor_idx[sb];
        float sa = 0.f, ss = 0.f;
        for (int base = 0; base < len; base += 64) {
            const int jmax = min(64, len - base);
            if (lane < jmax) {
                const float w = pw[off + base + lane];
                const int n = pn[off + base + lane];
                if (n == an) { sa += fabsf(w); ss += w; }
            }
        }
        #pragma unroll
        for (int m = 32; m; m >>= 1) {
            sa += __shfl_xor(sa, m);
            ss += __shfl_xor(ss, m);
        }
        const float denom = fmaxf(laWa - sa, 1e-12f);
        const float scale = (laWs - ss) / denom;
        const uint4 ha = *((const uint4*)(Hb + (size_t)an * DDIM) + s);
        float hv[8];
        unpack2(ha.x, hv[0], hv[1]);
        unpack2(ha.y, hv[2], hv[3]);
        unpack2(ha.z, hv[4], hv[5]);
        unpack2(ha.w, hv[6], hv[7]);
        float v[8];
        float n2 = 0.f;
        #pragma unroll
        for (int k = 0; k < 8; ++k) {
            v[k] = (acc[k] - sa * hv[k]) / denom;
            n2 = fmaf(v[k], v[k], n2);
        }
        #pragma unroll
        for (int m = 32; m; m >>= 1) n2 += __shfl_xor(n2, m);
        n2 *= 0.25f;
        const float na = sqrtf(n2);
        const float invA = 1.0f / fmaxf(na, 1e-6f);
        const float ns = fabsf(scale) * na;
        const float sgnscale = (ns > 0.f) ? (scale / fmaxf(ns, 1e-6f)) : scale;
        if (q == 0) {
            float4* oa = (float4*)(out + (size_t)sb * DDIM);
            oa[2 * s] = make_float4(v[0] * invA, v[1] * invA, v[2] * invA, v[3] * invA);
            oa[2 * s + 1] = make_float4(v[4] * invA, v[5] * invA, v[6] * invA, v[7] * invA);
        } else if (q == 1) {
            float4* os = (float4*)(out + ((size_t)B + sb) * DDIM);
            os[2 * s] = make_float4(v[0] * sgnscale, v[1] * sgnscale, v[2] * sgnscale, v[3] * sgnscale);
            os[2 * s + 1] = make_float4(v[4] * sgnscale, v[5] * sgnscale, v[6] * sgnscale, v[7] * sgnscale);
        }
    }
}

// ---- fp32 single-kernel fallback (ws too small or G > MAXG_LDS) ----
__global__ __launch_bounds__(1024) void scan_only(
    const int* __restrict__ len, int* __restrict__ offs, int G) {
    __shared__ int part[1024];
    const int t = threadIdx.x;
    const int chunk = (G + 1023) >> 10;
    const int lo = min(t * chunk, G);
    const int hi = min(lo + chunk, G);
    int s = 0;
    for (int i = lo; i < hi; ++i) s += len[i];
    part[t] = s;
    __syncthreads();
    #pragma unroll
    for (int ofs = 1; ofs < 1024; ofs <<= 1) {
        int v = (t >= ofs) ? part[t - ofs] : 0;
        __syncthreads();
        part[t] += v;
        __syncthreads();
    }
    int run = part[t] - s;
    for (int i = lo; i < hi; ++i) { offs[i] = run; run += len[i]; }
}

__global__ __launch_bounds__(256) void pf_loo_f32(
    const float* __restrict__ H, const float* __restrict__ pw,
    const int* __restrict__ anchor_idx, const int* __restrict__ pf_gid,
    const int* __restrict__ pn, const int* __restrict__ plen,
    const int* __restrict__ offs, float* __restrict__ out, int B, int G) {
    const int b = blockIdx.x * (blockDim.x >> 6) + (threadIdx.x >> 6);
    const int lane = threadIdx.x & 63;
    const int half = lane >> 5;
    const int qlane = lane & 31;
    if (b >= B) return;
    float4* outA = (float4*)(out + (size_t)b * DDIM);
    float4* outS = (float4*)(out + ((size_t)B + b) * DDIM);
    const int gid = pf_gid[b];
    if (!(gid >= 0 && gid < G)) {
        float4 z = make_float4(0.f, 0.f, 0.f, 0.f);
        if (half == 0) { outA[qlane] = z; outS[qlane] = z; }
        return;
    }
    const int anchor = anchor_idx[b];
    const int off = offs[gid];
    const int len = plen[gid];
    float4 acc = make_float4(0.f, 0.f, 0.f, 0.f);
    float laWa = 0.f, laWs = 0.f, laSa = 0.f, laSs = 0.f;
    for (int base = 0; base < len; base += 64) {
        const int jmax = min(64, len - base);
        float wl = 0.f;
        int nl = -1;
        if (lane < jmax) { wl = pw[off + base + lane]; nl = pn[off + base + lane]; }
        const float wla = fabsf(wl);
        laWa += wla; laWs += wl;
        if (nl == anchor) { laSa += wla; laSs += wl; }
        #pragma unroll 8
        for (int jj = 0; jj < 64; jj += 2) {
            const float ww = fabsf(__shfl(wl, jj + half));
            const int row = __shfl(nl, jj + half);
            const float4 h = ((const float4*)(H + (size_t)row * DDIM))[qlane];
            acc.x = fmaf(ww, h.x, acc.x);
            acc.y = fmaf(ww, h.y, acc.y);
            acc.z = fmaf(ww, h.z, acc.z);
            acc.w = fmaf(ww, h.w, acc.w);
        }
    }
    #pragma unroll
    for (int m = 32; m; m >>= 1) {
        laWa += __shfl_xor(laWa, m);
        laWs += __shfl_xor(laWs, m);
        laSa += __shfl_xor(laSa, m);
        laSs += __shfl_xor(laSs, m);
    }
    acc.x += __shfl_xor(acc.x, 32);
    acc.y += __shfl_xor(acc.y, 32);
    acc.z += __shfl_xor(acc.z, 32);
    acc.w += __shfl_xor(acc.w, 32);
    const float denom = fmaxf(laWa - laSa, 1e-12f);
    const float4 hv = ((const float4*)(H + (size_t)anchor * DDIM))[qlane];
    float4 v;
    v.x = (acc.x - laSa * hv.x) / denom;
    v.y = (acc.y - laSa * hv.y) / denom;
    v.z = (acc.z - laSa * hv.z) / denom;
    v.w = (acc.w - laSa * hv.w) / denom;
    const float scale = (laWs - laSs) / denom;
    float n2 = v.x * v.x + v.y * v.y + v.z * v.z + v.w * v.w;
    #pragma unroll
    for (int m = 32; m; m >>= 1) n2 += __shfl_xor(n2, m);
    n2 *= 0.5f;
    const float na = sqrtf(n2);
    const float invA = 1.0f / fmaxf(na, 1e-6f);
    const float ns = fabsf(scale) * na;
    const float sgnscale = (ns > 0.f) ? (scale / fmaxf(ns, 1e-6f)) : scale;
    const float sc = half ? sgnscale : invA;
    float4 res = make_float4(v.x * sc, v.y * sc, v.z * sc, v.w * sc);
    float4* dst = half ? outS : outA;
    dst[qlane] = res;
}

extern "C" void kernel_launch(void* const* d_in, const int* in_sizes, int n_in,
                              void* d_out, int out_size, void* d_ws, size_t ws_size,
                              hipStream_t stream) {
    const float* H      = (const float*)d_in[0];
    const float* pw     = (const float*)d_in[1];
    const int* anchor   = (const int*)d_in[2];
    const int* gid      = (const int*)d_in[3];
    const int* pn       = (const int*)d_in[4];
    const int* plen     = (const int*)d_in[5];
    float* out          = (float*)d_out;

    const int B = in_sizes[2];
    const int G = in_sizes[5];
    const int ND = in_sizes[0];                 // N*128 floats
    const size_t hb_bytes = (size_t)ND * 2;     // bf16 H
    const size_t need = hb_bytes + (size_t)(G + 1) * 4 + (size_t)B * 4 +
                        (size_t)G * 4;

    if (ws_size >= need && G <= MAXG_LDS) {
        char* p = (char*)d_ws;
        unsigned short* Hb = (unsigned short*)p;  p += hb_bytes;
        int* sstart        = (int*)p;             p += (size_t)(G + 1) * 4;
        int* slist         = (int*)p;             p += (size_t)B * 4;
        int* offsp         = (int*)p;

        const int n4 = ND / 4;
        const int nconv = (n4 + 1023) / 1024;
        init_kernel<<<nconv + 2, 1024, 0, stream>>>(
            (const float4*)H, (uint2*)Hb, n4, plen, offsp, G, gid,
            sstart, slist, out, B, nconv);

        const int gblocks = (G + 3) / 4;
        group_fused<<<gblocks, 256, 0, stream>>>(Hb, pw, pn, plen, offsp,
                                                 sstart, slist, anchor,
                                                 out, B, G);
    } else {
        int* offsp = (int*)d_ws;
        scan_only<<<1, 1024, 0, stream>>>(plen, offsp, G);
        const int blocks = (B + 3) / 4;
        pf_loo_f32<<<blocks, 256, 0, stream>>>(H, pw, anchor, gid, pn, plen,
                                               offsp, out, B, G);
    }
}

// Round 6
// 142.604 us; speedup vs baseline: 1.0925x; 1.0925x over previous
//
#include <hip/hip_runtime.h>
#include <hip/hip_bf16.h>

// Problem: MultiViewDGT_51745765982512
//   d_in[0] H [N,128] f32, d_in[1] port_w [L] f32, d_in[2] anchor [B] i32,
//   d_in[3] pf_gid [B] i32, d_in[4] port_nodes [L] i32, d_in[5] port_len [G] i32
//   out = concat(V_abs [B,128], V_sgn [B,128]) f32
//
// R6: revert R5's fusion (regressed: init +8us, group +9.5us). R5 counters
// showed the group gather is LATENCY-bound (FETCH 72MB @ 1.6 TB/s, VALUBusy
// 29% — nothing saturated). So: R4 pipeline + 2 waves per group (128-thr
// block, each wave 32 lines = 8 fully-unrolled 4-row dwordx4 gathers, LDS
// combine) -> 2x independent load streams to hide L3/HBM miss latency.

#define DDIM 128

__device__ inline unsigned bf_rne(float x) {
    unsigned u = __float_as_uint(x);
    return (u + 0x7FFFu + ((u >> 16) & 1u)) >> 16;
}

__device__ inline void unpack2(unsigned d, float& lo, float& hi) {
    lo = __uint_as_float(d << 16);
    hi = __uint_as_float(d & 0xFFFF0000u);
}

// Block roles: [0, nconv) convert H->bf16; nconv: used-flags; nconv+1: scan.
__global__ __launch_bounds__(1024) void init_kernel(
    const float4* __restrict__ H4, uint2* __restrict__ Hb, int n4,
    const int* __restrict__ plen, int* __restrict__ offs, int G,
    const int* __restrict__ pf_gid, int* __restrict__ used, int B, int nconv) {
    const int t = threadIdx.x;
    const int bb = blockIdx.x;
    if (bb < nconv) {
        const int i = bb * 1024 + t;
        if (i < n4) {
            const float4 v = H4[i];
            uint2 o;
            o.x = bf_rne(v.x) | (bf_rne(v.y) << 16);
            o.y = bf_rne(v.z) | (bf_rne(v.w) << 16);
            Hb[i] = o;
        }
        return;
    }
    if (bb == nconv) {
        for (int i = t; i < G; i += 1024) used[i] = 0;
        __syncthreads();
        for (int i = t; i < B; i += 1024) {
            const int g = pf_gid[i];
            if (g >= 0 && g < G) used[g] = 1;
        }
        return;
    }
    // scan role: exclusive prefix sum of plen -> offs
    __shared__ int part[1024];
    const int chunk = (G + 1023) >> 10;
    const int lo = min(t * chunk, G);
    const int hi = min(lo + chunk, G);
    int s = 0;
    for (int i = lo; i < hi; ++i) s += plen[i];
    part[t] = s;
    __syncthreads();
    #pragma unroll
    for (int ofs = 1; ofs < 1024; ofs <<= 1) {
        int v = (t >= ofs) ? part[t - ofs] : 0;
        __syncthreads();
        part[t] += v;
        __syncthreads();
    }
    int run = part[t] - s;
    for (int i = lo; i < hi; ++i) { offs[i] = run; run += plen[i]; }
}

// One 128-thread block (2 waves) per used group. Wave wid handles lines
// [base + 32*wid, base + 32*wid + 32). Gather: 4 rows per dwordx4
// (quarter q=lane>>4 takes row jj+q, s=lane&15 owns dims [8s,8s+8));
// jj loop fully unrolled -> 8 dwordx4 in flight per wave. Partials
// combined via LDS.
__global__ __launch_bounds__(128) void group_sums(
    const unsigned short* __restrict__ Hb,
    const float* __restrict__ pw, const int* __restrict__ pn,
    const int* __restrict__ plen, const int* __restrict__ offs,
    const int* __restrict__ used,
    float* __restrict__ Sabs, float* __restrict__ Wag,
    float* __restrict__ Wsg, int G) {
    const int g = blockIdx.x;
    if (g >= G || !used[g]) return;
    const int tid = threadIdx.x;
    const int wid = tid >> 6;
    const int lane = tid & 63;
    const int q = lane >> 4;
    const int s = lane & 15;

    __shared__ float ldsS[2][DDIM];
    __shared__ float ldsW[4];

    const int off = offs[g];
    const int len = plen[g];

    float acc[8] = {0.f, 0.f, 0.f, 0.f, 0.f, 0.f, 0.f, 0.f};
    float laWa = 0.f, laWs = 0.f;

    for (int base = 0; base < len; base += 64) {
        const int l0 = base + wid * 32;
        // lanes 0..31 preload one (w,node) each for this wave's 32 lines
        float wl = 0.f;
        int nl = 0;   // padding: w=0 contributes nothing; row-0 load harmless
        if (lane < 32 && l0 + lane < len) {
            wl = pw[off + l0 + lane];
            nl = pn[off + l0 + lane];
        }
        laWa += fabsf(wl);
        laWs += wl;

        #pragma unroll
        for (int jj = 0; jj < 32; jj += 4) {
            const float ww = fabsf(__shfl(wl, jj + q));
            const int row = __shfl(nl, jj + q);
            const uint4 h = *((const uint4*)(Hb + (size_t)row * DDIM) + s);
            float f0, f1, f2, f3, f4, f5, f6, f7;
            unpack2(h.x, f0, f1);
            unpack2(h.y, f2, f3);
            unpack2(h.z, f4, f5);
            unpack2(h.w, f6, f7);
            acc[0] = fmaf(ww, f0, acc[0]);
            acc[1] = fmaf(ww, f1, acc[1]);
            acc[2] = fmaf(ww, f2, acc[2]);
            acc[3] = fmaf(ww, f3, acc[3]);
            acc[4] = fmaf(ww, f4, acc[4]);
            acc[5] = fmaf(ww, f5, acc[5]);
            acc[6] = fmaf(ww, f6, acc[6]);
            acc[7] = fmaf(ww, f7, acc[7]);
        }
    }

    // stats butterfly (lanes 32..63 hold zeros -> still correct)
    #pragma unroll
    for (int m = 32; m; m >>= 1) {
        laWa += __shfl_xor(laWa, m);
        laWs += __shfl_xor(laWs, m);
    }
    // combine the 4 quarters of this wave
    #pragma unroll
    for (int k = 0; k < 8; ++k) {
        acc[k] += __shfl_xor(acc[k], 16);
        acc[k] += __shfl_xor(acc[k], 32);
    }

    if (q == 0) {
        #pragma unroll
        for (int k = 0; k < 8; ++k) ldsS[wid][8 * s + k] = acc[k];
    }
    if (lane == 0) { ldsW[wid] = laWa; ldsW[2 + wid] = laWs; }
    __syncthreads();

    if (tid < DDIM) {
        Sabs[(size_t)g * DDIM + tid] = ldsS[0][tid] + ldsS[1][tid];
    }
    if (tid == 0) {
        Wag[g] = ldsW[0] + ldsW[1];
        Wsg[g] = ldsW[2] + ldsW[3];
    }
}

// One wave per sample: LOO + epilogue. Lane owns dims [2l, 2l+1].
__global__ __launch_bounds__(256) void per_sample(
    const unsigned short* __restrict__ Hb,
    const float* __restrict__ pw, const int* __restrict__ pn,
    const int* __restrict__ plen, const int* __restrict__ offs,
    const float* __restrict__ Sabs, const float* __restrict__ Wag,
    const float* __restrict__ Wsg,
    const int* __restrict__ anchor_idx, const int* __restrict__ pf_gid,
    float* __restrict__ out, int B, int G) {
    const int b = blockIdx.x * (blockDim.x >> 6) + (threadIdx.x >> 6);
    const int lane = threadIdx.x & 63;
    if (b >= B) return;

    float2* outA = (float2*)(out + (size_t)b * DDIM);
    float2* outS = (float2*)(out + ((size_t)B + b) * DDIM);

    const int g = pf_gid[b];
    if (!(g >= 0 && g < G)) {
        const float2 z = make_float2(0.f, 0.f);
        outA[lane] = z;
        outS[lane] = z;
        return;
    }

    const int anchor = anchor_idx[b];
    const int off = offs[g];
    const int len = plen[g];

    float selfa = 0.f, selfs = 0.f;
    for (int base = 0; base < len; base += 64) {
        const int jmax = min(64, len - base);
        if (lane < jmax) {
            const float w = pw[off + base + lane];
            const int n = pn[off + base + lane];
            if (n == anchor) { selfa += fabsf(w); selfs += w; }
        }
    }
    #pragma unroll
    for (int m = 32; m; m >>= 1) {
        selfa += __shfl_xor(selfa, m);
        selfs += __shfl_xor(selfs, m);
    }

    const float Wa = Wag[g];
    const float Wsn = Wsg[g];
    const float2 S = ((const float2*)(Sabs + (size_t)g * DDIM))[lane];
    const unsigned hb = *((const unsigned*)(Hb + (size_t)anchor * DDIM) + lane);
    float h0, h1;
    unpack2(hb, h0, h1);

    const float denom = fmaxf(Wa - selfa, 1e-12f);
    float2 v;
    v.x = (S.x - selfa * h0) / denom;
    v.y = (S.y - selfa * h1) / denom;
    const float scale = (Wsn - selfs) / denom;

    float n2 = v.x * v.x + v.y * v.y;
    #pragma unroll
    for (int m = 32; m; m >>= 1) n2 += __shfl_xor(n2, m);
    const float na = sqrtf(n2);

    const float invA = 1.0f / fmaxf(na, 1e-6f);
    const float ns = fabsf(scale) * na;
    const float sgnscale = (ns > 0.f) ? (scale / fmaxf(ns, 1e-6f)) : scale;

    outA[lane] = make_float2(v.x * invA, v.y * invA);
    outS[lane] = make_float2(v.x * sgnscale, v.y * sgnscale);
}

// ---- fp32 single-kernel fallback (ws too small) ----
__global__ __launch_bounds__(1024) void scan_only(
    const int* __restrict__ len, int* __restrict__ offs, int G) {
    __shared__ int part[1024];
    const int t = threadIdx.x;
    const int chunk = (G + 1023) >> 10;
    const int lo = min(t * chunk, G);
    const int hi = min(lo + chunk, G);
    int s = 0;
    for (int i = lo; i < hi; ++i) s += len[i];
    part[t] = s;
    __syncthreads();
    #pragma unroll
    for (int ofs = 1; ofs < 1024; ofs <<= 1) {
        int v = (t >= ofs) ? part[t - ofs] : 0;
        __syncthreads();
        part[t] += v;
        __syncthreads();
    }
    int run = part[t] - s;
    for (int i = lo; i < hi; ++i) { offs[i] = run; run += len[i]; }
}

__global__ __launch_bounds__(256) void pf_loo_f32(
    const float* __restrict__ H, const float* __restrict__ pw,
    const int* __restrict__ anchor_idx, const int* __restrict__ pf_gid,
    const int* __restrict__ pn, const int* __restrict__ plen,
    const int* __restrict__ offs, float* __restrict__ out, int B, int G) {
    const int b = blockIdx.x * (blockDim.x >> 6) + (threadIdx.x >> 6);
    const int lane = threadIdx.x & 63;
    const int half = lane >> 5;
    const int qlane = lane & 31;
    if (b >= B) return;
    float4* outA = (float4*)(out + (size_t)b * DDIM);
    float4* outS = (float4*)(out + ((size_t)B + b) * DDIM);
    const int gid = pf_gid[b];
    if (!(gid >= 0 && gid < G)) {
        float4 z = make_float4(0.f, 0.f, 0.f, 0.f);
        if (half == 0) { outA[qlane] = z; outS[qlane] = z; }
        return;
    }
    const int anchor = anchor_idx[b];
    const int off = offs[gid];
    const int len = plen[gid];
    float4 acc = make_float4(0.f, 0.f, 0.f, 0.f);
    float laWa = 0.f, laWs = 0.f, laSa = 0.f, laSs = 0.f;
    for (int base = 0; base < len; base += 64) {
        const int jmax = min(64, len - base);
        float wl = 0.f;
        int nl = -1;
        if (lane < jmax) { wl = pw[off + base + lane]; nl = pn[off + base + lane]; }
        const float wla = fabsf(wl);
        laWa += wla; laWs += wl;
        if (nl == anchor) { laSa += wla; laSs += wl; }
        #pragma unroll 8
        for (int jj = 0; jj < 64; jj += 2) {
            const float ww = fabsf(__shfl(wl, jj + half));
            const int row = __shfl(nl, jj + half);
            const float4 h = ((const float4*)(H + (size_t)row * DDIM))[qlane];
            acc.x = fmaf(ww, h.x, acc.x);
            acc.y = fmaf(ww, h.y, acc.y);
            acc.z = fmaf(ww, h.z, acc.z);
            acc.w = fmaf(ww, h.w, acc.w);
        }
    }
    #pragma unroll
    for (int m = 32; m; m >>= 1) {
        laWa += __shfl_xor(laWa, m);
        laWs += __shfl_xor(laWs, m);
        laSa += __shfl_xor(laSa, m);
        laSs += __shfl_xor(laSs, m);
    }
    acc.x += __shfl_xor(acc.x, 32);
    acc.y += __shfl_xor(acc.y, 32);
    acc.z += __shfl_xor(acc.z, 32);
    acc.w += __shfl_xor(acc.w, 32);
    const float denom = fmaxf(laWa - laSa, 1e-12f);
    const float4 hv = ((const float4*)(H + (size_t)anchor * DDIM))[qlane];
    float4 v;
    v.x = (acc.x - laSa * hv.x) / denom;
    v.y = (acc.y - laSa * hv.y) / denom;
    v.z = (acc.z - laSa * hv.z) / denom;
    v.w = (acc.w - laSa * hv.w) / denom;
    const float scale = (laWs - laSs) / denom;
    float n2 = v.x * v.x + v.y * v.y + v.z * v.z + v.w * v.w;
    #pragma unroll
    for (int m = 32; m; m >>= 1) n2 += __shfl_xor(n2, m);
    n2 *= 0.5f;
    const float na = sqrtf(n2);
    const float invA = 1.0f / fmaxf(na, 1e-6f);
    const float ns = fabsf(scale) * na;
    const float sgnscale = (ns > 0.f) ? (scale / fmaxf(ns, 1e-6f)) : scale;
    const float sc = half ? sgnscale : invA;
    float4 res = make_float4(v.x * sc, v.y * sc, v.z * sc, v.w * sc);
    float4* dst = half ? outS : outA;
    dst[qlane] = res;
}

extern "C" void kernel_launch(void* const* d_in, const int* in_sizes, int n_in,
                              void* d_out, int out_size, void* d_ws, size_t ws_size,
                              hipStream_t stream) {
    const float* H      = (const float*)d_in[0];
    const float* pw     = (const float*)d_in[1];
    const int* anchor   = (const int*)d_in[2];
    const int* gid      = (const int*)d_in[3];
    const int* pn       = (const int*)d_in[4];
    const int* plen     = (const int*)d_in[5];
    float* out          = (float*)d_out;

    const int B = in_sizes[2];
    const int G = in_sizes[5];
    const int ND = in_sizes[0];                 // N*128 floats
    const size_t hb_bytes = (size_t)ND * 2;     // bf16 H
    const size_t sabs_bytes = (size_t)G * DDIM * 4;
    const size_t need = hb_bytes + sabs_bytes + (size_t)G * 4 * 4;

    if (ws_size >= need) {
        char* p = (char*)d_ws;
        unsigned short* Hb = (unsigned short*)p;        p += hb_bytes;
        float* Sabs        = (float*)p;                 p += sabs_bytes;
        int* offsp         = (int*)p;                   p += (size_t)G * 4;
        int* usedp         = (int*)p;                   p += (size_t)G * 4;
        float* Wag         = (float*)p;                 p += (size_t)G * 4;
        float* Wsg         = (float*)p;

        const int n4 = ND / 4;
        const int nconv = (n4 + 1023) / 1024;
        init_kernel<<<nconv + 2, 1024, 0, stream>>>(
            (const float4*)H, (uint2*)Hb, n4, plen, offsp, G, gid, usedp, B, nconv);

        group_sums<<<G, 128, 0, stream>>>(Hb, pw, pn, plen, offsp, usedp,
                                          Sabs, Wag, Wsg, G);

        const int sblocks = (B + 3) / 4;
        per_sample<<<sblocks, 256, 0, stream>>>(Hb, pw, pn, plen, offsp, Sabs,
                                                Wag, Wsg, anchor, gid, out, B, G);
    } else {
        int* offsp = (int*)d_ws;
        scan_only<<<1, 1024, 0, stream>>>(plen, offsp, G);
        const int blocks = (B + 3) / 4;
        pf_loo_f32<<<blocks, 256, 0, stream>>>(H, pw, anchor, gid, pn, plen,
                                               offsp, out, B, G);
    }
}